// Round 2
// baseline (19.348 us; speedup 1.0000x reference)
//
#include <hip/hip_runtime.h>

#define POS_THR 0.7f

// One thread per PAIR of boxes (b, 2t), (b, 2t+1).
// - gt boxes read directly from global at wave-uniform addresses -> s_load
//   (no LDS, no __syncthreads, no per-iteration ds_read latency).
// - No data-dependent break: full-G loop, unrolled x4 -> 8 independent
//   IoU/division chains in flight per thread.
// - IoU uses the reference's exact fp32 op order: clip = min(max(.)),
//   union = (area + ga) - inter, true IEEE division, >= 0.7f.
__global__ __launch_bounds__(256) void assign_cls_kernel(
    const float4* __restrict__ bbox,      // [B, N] of (y1,x1,y2,x2)
    const float4* __restrict__ gt,        // [B, A]
    const int*    __restrict__ gt_counts, // [B]
    const int*    __restrict__ counts,    // [B]
    int2*         __restrict__ out,       // [B, N/2]
    int N, int A)
{
    const int b  = blockIdx.y;
    const int t  = blockIdx.x * blockDim.x + threadIdx.x;
    const int n0 = t * 2;
    if (n0 >= N) return;

    const int G   = min(gt_counts[b], A);  // only valid gt boxes matter
    const int cnt = counts[b];             // block-uniform

    int l0 = 0, l1 = 0;
    if (n0 < cnt) {
        const float4 b0 = bbox[(size_t)b * N + n0];
        const float4 b1 = bbox[(size_t)b * N + n0 + 1];
        const float a0 = (b0.z - b0.x) * (b0.w - b0.y);
        const float a1 = (b1.z - b1.x) * (b1.w - b1.y);
        const float4* gtb = gt + (size_t)b * A;

        #pragma unroll 4
        for (int g = 0; g < G; ++g) {
            const float4 gb = gtb[g];                 // uniform addr -> s_load
            const float ga = (gb.z - gb.x) * (gb.w - gb.y);
            {
                const float yy1 = fminf(fmaxf(b0.x, gb.x), gb.z);
                const float xx1 = fminf(fmaxf(b0.y, gb.y), gb.w);
                const float yy2 = fminf(fmaxf(b0.z, gb.x), gb.z);
                const float xx2 = fminf(fmaxf(b0.w, gb.y), gb.w);
                const float inter = (yy2 - yy1) * (xx2 - xx1);
                const float uni   = (a0 + ga) - inter;
                l0 |= (inter / uni >= POS_THR);
            }
            {
                const float yy1 = fminf(fmaxf(b1.x, gb.x), gb.z);
                const float xx1 = fminf(fmaxf(b1.y, gb.y), gb.w);
                const float yy2 = fminf(fmaxf(b1.z, gb.x), gb.z);
                const float xx2 = fminf(fmaxf(b1.w, gb.y), gb.w);
                const float inter = (yy2 - yy1) * (xx2 - xx1);
                const float uni   = (a1 + ga) - inter;
                l1 |= (inter / uni >= POS_THR);
            }
        }
        if (n0 + 1 >= cnt) l1 = 0;  // second box beyond per-batch count
    }
    out[(size_t)b * (N >> 1) + t] = make_int2(l0, l1);
}

extern "C" void kernel_launch(void* const* d_in, const int* in_sizes, int n_in,
                              void* d_out, int out_size, void* d_ws, size_t ws_size,
                              hipStream_t stream) {
    const float4* bbox      = (const float4*)d_in[0];
    const float4* gt        = (const float4*)d_in[1];
    const int*    gt_counts = (const int*)d_in[2];
    const int*    counts    = (const int*)d_in[3];
    int2*         out       = (int2*)d_out;

    const int B = in_sizes[2];               // gt_counts has B elements
    const int A = in_sizes[1] / (4 * B);     // 64
    const int N = in_sizes[0] / (4 * B);     // 65536

    const int pairs = N >> 1;                // 2 boxes per thread
    dim3 block(256, 1, 1);
    dim3 grid((pairs + 255) / 256, B, 1);
    assign_cls_kernel<<<grid, block, 0, stream>>>(bbox, gt, gt_counts, counts,
                                                  out, N, A);
}

// Round 3
// 18.970 us; speedup vs baseline: 1.0199x; 1.0199x over previous
//
#include <hip/hip_runtime.h>

#define POS_THR 0.7f
#define MAX_A 64

// 1 box/thread, 2048 blocks (8 waves/SIMD) for latency hiding.
// gt boxes + precomputed gt areas staged once in LDS; inner loop is pure
// ds_read + VALU, no break, unrolled x4 for ILP.
// IoU keeps the reference's exact fp32 op order: clip = min(max(.)),
// union = (area + ga) - inter, true IEEE division, >= 0.7f.
__global__ __launch_bounds__(256) void assign_cls_kernel(
    const float4* __restrict__ bbox,      // [B, N] of (y1,x1,y2,x2)
    const float4* __restrict__ gt,        // [B, A]
    const int*    __restrict__ gt_counts, // [B]
    const int*    __restrict__ counts,    // [B]
    int*          __restrict__ out,       // [B, N]
    int N, int A)
{
    const int b = blockIdx.y;
    const int n = blockIdx.x * blockDim.x + threadIdx.x;
    const int cnt = counts[b];            // block-uniform scalar

    // Whole-block early out: every box in this block is beyond cnt -> label 0.
    // Block-uniform condition, so no divergence; frees the SIMD immediately.
    if ((int)(blockIdx.x * blockDim.x) >= cnt) {
        out[(size_t)b * N + n] = 0;
        return;
    }

    __shared__ float4 sgt[MAX_A];
    __shared__ float  sga[MAX_A];
    if (threadIdx.x < (unsigned)A) {
        float4 g = gt[(size_t)b * A + threadIdx.x];
        sgt[threadIdx.x] = g;
        sga[threadIdx.x] = (g.z - g.x) * (g.w - g.y);  // ga
    }
    __syncthreads();

    const int G = min(gt_counts[b], A);

    int label = 0;
    if (n < cnt) {
        const float4 bb = bbox[(size_t)b * N + n];     // coalesced dwordx4
        const float area = (bb.z - bb.x) * (bb.w - bb.y);

        #pragma unroll 4
        for (int g = 0; g < G; ++g) {
            const float4 gb = sgt[g];                  // ds_read_b128, bcast
            const float yy1 = fminf(fmaxf(bb.x, gb.x), gb.z);
            const float xx1 = fminf(fmaxf(bb.y, gb.y), gb.w);
            const float yy2 = fminf(fmaxf(bb.z, gb.x), gb.z);
            const float xx2 = fminf(fmaxf(bb.w, gb.y), gb.w);
            const float inter = (yy2 - yy1) * (xx2 - xx1);
            const float uni   = (area + sga[g]) - inter;
            label |= (inter / uni >= POS_THR);         // exact IEEE div
        }
    }
    out[(size_t)b * N + n] = label;
}

extern "C" void kernel_launch(void* const* d_in, const int* in_sizes, int n_in,
                              void* d_out, int out_size, void* d_ws, size_t ws_size,
                              hipStream_t stream) {
    const float4* bbox      = (const float4*)d_in[0];
    const float4* gt        = (const float4*)d_in[1];
    const int*    gt_counts = (const int*)d_in[2];
    const int*    counts    = (const int*)d_in[3];
    int*          out       = (int*)d_out;

    const int B = in_sizes[2];               // gt_counts has B elements
    const int A = in_sizes[1] / (4 * B);     // 64
    const int N = in_sizes[0] / (4 * B);     // 65536

    dim3 block(256, 1, 1);
    dim3 grid((N + 255) / 256, B, 1);        // 2048 blocks
    assign_cls_kernel<<<grid, block, 0, stream>>>(bbox, gt, gt_counts, counts,
                                                  out, N, A);
}